// Round 7
// baseline (244.525 us; speedup 1.0000x reference)
//
#include <hip/hip_runtime.h>

// P2G quadratic B-spline scatter, MI355X — v6: XCD-batch-partitioned binning.
//
// v5 post-mortem: K2's CAS-loop removed (native ds_add_u64 confirmed); new
// top dispatch is K1 bin_particles_mat: WRITE_SIZE 59.5 MB for 16 MB payload
// = full-line write-allocate per scattered 16B store, because the ~4 appends
// per 64B slot line come from random XCDs and the line bounces to HBM
// between them. v6 exploits bin = batch*512 + spatial with batch uniform in
// [0,B): class k = blockIdx%B (round-robin block->XCD) scans ALL particles,
// keeps batch==k, so every append to a given slot line is issued from ONE
// XCD -> line accumulates all 4 appends in that XCD's L2 before writeback.
// K2/K3 use the same %B swizzle so slots/tiles stay XCD-local across stages.
// XCD mapping is a perf heuristic only — correctness never depends on it.
//   K1: B*256 blocks; class k scans stripes of all particles, filters
//       bidx==k, appends {px,py,pz,prob} to batch-k bin slots.
//   K2: B*512 blocks, bin = (blk%B)*512 + blk/B; coalesced slot reads;
//       27 taps x 2 native ds_add_u64 into 10^3 LDS tile; float2 store.
//   K3: B*1024 blocks, batch = blk%B; fp32-sum 1..8 covering tiles, divide.
// Fallback (ws too small): v1 interleaved global-atomic path.

namespace {

constexpr int   G        = 64;
constexpr int   G3       = G * G * G;            // 262144
constexpr int   BIN      = 8;                    // cells per bin per axis
constexpr int   NBX      = G / BIN;              // 8 bins per axis
constexpr int   BINS_PB  = NBX * NBX * NBX;      // 512 bins per batch
constexpr int   TILE     = BIN + 2;              // 10 (halo -1..8)
constexpr int   TILE3    = TILE * TILE * TILE;   // 1000
constexpr int   CAP      = 512;                  // slots per bin (avg ~244)
constexpr float EPS_CLIP = 1e-5f;
constexpr float EPS_DIV  = 1e-7f;
constexpr float INV_DX   = 64.0f;                // 1/DX (exact pow2)
constexpr float FXS      = 4398046511104.0f;     // 2^42 fixed-point scale
constexpr float INV_FXS  = 1.0f / FXS;           // 2^-42

__device__ __forceinline__ float clip01(float v) {
    return fminf(fmaxf(v, EPS_CLIP), 1.0f - EPS_CLIP);
}

__device__ __forceinline__ void bspline_w(float f, float* w) {
    w[0] = 0.5f * (1.0f - f) * (1.0f - f);
    w[1] = 0.75f - (f - 0.5f) * (f - 0.5f);
    w[2] = 0.5f * f * f;
}

// ---------------- K1: XCD-class-filtered binning --------------------------
// grid = B * STRIPES blocks; class k = blockIdx % B handles only batch k.
// Stripe s = blockIdx / B covers particles [s*chunk, (s+1)*chunk).
constexpr int STRIPES = 256;

__global__ void __launch_bounds__(256)
bin_particles_xcd(const float* __restrict__ pos,
                  const float* __restrict__ prob,
                  const int*   __restrict__ bidx,
                  int*         __restrict__ cnt,    // nbins
                  float4*      __restrict__ slots,  // nbins*CAP
                  int L, int B) {
    const int k = blockIdx.x % B;              // batch class (== XCD if B==8)
    const int s = blockIdx.x / B;              // stripe
    const int chunk = (L + STRIPES - 1) / STRIPES;
    const int lo = s * chunk;
    const int hi = min(lo + chunk, L);

    for (int i = lo + (int)threadIdx.x; i < hi; i += 256) {
        if (bidx[i] != k) continue;
        float px = pos[3 * i + 0];
        float py = pos[3 * i + 1];
        float pz = pos[3 * i + 2];
        int bx = (int)(clip01(px) * INV_DX);
        int by = (int)(clip01(py) * INV_DX);
        int bz = (int)(clip01(pz) * INV_DX);
        int bin = ((k * NBX + (bx >> 3)) * NBX + (by >> 3)) * NBX + (bz >> 3);
        int slot = atomicAdd(&cnt[bin], 1);
        if (slot < CAP)
            slots[(size_t)bin * CAP + slot] = make_float4(px, py, pz, prob[i]);
    }
}

// ---------------- K2: per-bin LDS tile accumulation (2x ds_add_u64) -------
// grid = B * BINS_PB; bin = (blockIdx%B)*BINS_PB + blockIdx/B keeps batch-k
// bins on XCD k (slot lines still resident in that L2 from K1).

__global__ void __launch_bounds__(256)
accumulate_bins(const float4* __restrict__ slots,
                const int*    __restrict__ cnt,
                float2*       __restrict__ tiles,    // nbins*TILE3
                int B) {
    __shared__ unsigned long long t_w[TILE3];
    __shared__ unsigned long long t_wp[TILE3];
    const int bin = (blockIdx.x % B) * BINS_PB + blockIdx.x / B;
    const int tid = threadIdx.x;

    for (int j = tid; j < TILE3; j += 256) { t_w[j] = 0ull; t_wp[j] = 0ull; }
    __syncthreads();

    const int n = min(cnt[bin], CAP);
    // bin origin in cells (bin = ((b*8+bbx)*8+bby)*8+bbz)
    const int bx0 = ((bin >> 6) & 7) * BIN;
    const int by0 = ((bin >> 3) & 7) * BIN;
    const int bz0 = (bin & 7) * BIN;
    const float4* sbase = slots + (size_t)bin * CAP;

    for (int s = tid; s < n; s += 256) {
        float4 r = sbase[s];                         // coalesced 16B load
        float xp = clip01(r.x) * INV_DX;
        float yp = clip01(r.y) * INV_DX;
        float zp = clip01(r.z) * INV_DX;
        int bx = (int)xp, by = (int)yp, bz = (int)zp;
        float wx[3], wy[3], wz[3];
        bspline_w(xp - (float)bx, wx);
        bspline_w(yp - (float)by, wy);
        bspline_w(zp - (float)bz, wz);
        float p = r.w;
        // local base, pre-offset so tap index = l0 + a directly in [0, 9]
        int l0x = bx - bx0, l0y = by - by0, l0z = bz - bz0;
#pragma unroll
        for (int a = 0; a < 3; ++a) {
            int ix = (l0x + a) * TILE;
#pragma unroll
            for (int c = 0; c < 3; ++c) {
                int ixy = (ix + l0y + c) * TILE;
                float wxy = wx[a] * wy[c];
#pragma unroll
                for (int e = 0; e < 3; ++e) {
                    float w  = wxy * wz[e];
                    int   ci = ixy + l0z + e;
                    atomicAdd(&t_w[ci],  (unsigned long long)(w * FXS));
                    atomicAdd(&t_wp[ci], (unsigned long long)(w * p * FXS));
                }
            }
        }
    }
    __syncthreads();

    float2* gt = tiles + (size_t)bin * TILE3;
    for (int j = tid; j < TILE3; j += 256) {
        gt[j] = make_float2((float)t_w[j] * INV_FXS, (float)t_wp[j] * INV_FXS);
    }
}

// ---------------- K3: gather overlapping tiles + divide -------------------
// grid = B * (G3/256); batch = blockIdx%B so batch-k tile reads stay on XCD k.

__global__ void __launch_bounds__(256)
finalize_tiles(const float2* __restrict__ tiles,
               float*        __restrict__ out,
               int B) {
    const int b   = blockIdx.x % B;
    const int blk = blockIdx.x / B;
    const int c   = blk * 256 + (int)threadIdx.x;   // cell within batch
    int cz = c & 63, cy = (c >> 6) & 63, cx = (c >> 12) & 63;
    int bx = cx >> 3, mx = cx & 7;
    int by = cy >> 3, my = cy & 7;
    int bz = cz >> 3, mz = cz & 7;

    // per-axis list of (bin coord, tile-local index) covering this cell
    int xb[2], xl[2], nx = 1; xb[0] = bx; xl[0] = mx + 1;
    if (mx == 0 && bx > 0)       { xb[1] = bx - 1; xl[1] = 9; nx = 2; }
    else if (mx == 7 && bx < 7)  { xb[1] = bx + 1; xl[1] = 0; nx = 2; }
    int yb[2], yl[2], ny = 1; yb[0] = by; yl[0] = my + 1;
    if (my == 0 && by > 0)       { yb[1] = by - 1; yl[1] = 9; ny = 2; }
    else if (my == 7 && by < 7)  { yb[1] = by + 1; yl[1] = 0; ny = 2; }
    int zb[2], zl[2], nz = 1; zb[0] = bz; zl[0] = mz + 1;
    if (mz == 0 && bz > 0)       { zb[1] = bz - 1; zl[1] = 9; nz = 2; }
    else if (mz == 7 && bz < 7)  { zb[1] = bz + 1; zl[1] = 0; nz = 2; }

    float w = 0.f, wp = 0.f;
    for (int i = 0; i < nx; ++i)
        for (int j = 0; j < ny; ++j)
            for (int kk = 0; kk < nz; ++kk) {
                int bin = ((b * NBX + xb[i]) * NBX + yb[j]) * NBX + zb[kk];
                float2 v = tiles[(size_t)bin * TILE3
                                 + (xl[i] * TILE + yl[j]) * TILE + zl[kk]];
                w += v.x; wp += v.y;
            }
    out[b * G3 + c] = wp / (w + EPS_DIV);
}

// ---------------- fallback kernels (v1) -----------------------------------

__global__ void scatter_interleaved(const float* __restrict__ pos,
                                    const float* __restrict__ prob,
                                    const int*   __restrict__ bidx,
                                    float2*      __restrict__ grid,
                                    int L) {
    int i = blockIdx.x * blockDim.x + threadIdx.x;
    if (i >= L) return;
    float xp = clip01(pos[3 * i + 0]) * INV_DX;
    float yp = clip01(pos[3 * i + 1]) * INV_DX;
    float zp = clip01(pos[3 * i + 2]) * INV_DX;
    int bx = (int)xp, by = (int)yp, bz = (int)zp;
    float wx[3], wy[3], wz[3];
    bspline_w(xp - (float)bx, wx);
    bspline_w(yp - (float)by, wy);
    bspline_w(zp - (float)bz, wz);
    float p = prob[i];
    float2* gbase = grid + (size_t)bidx[i] * G3;
#pragma unroll
    for (int a = 0; a < 3; ++a) {
        int tx = bx + a - 1;
        if (tx < 0 || tx >= G) continue;
#pragma unroll
        for (int c = 0; c < 3; ++c) {
            int ty = by + c - 1;
            if (ty < 0 || ty >= G) continue;
            float wxy = wx[a] * wy[c];
            int rowoff = (tx * G + ty) * G;
#pragma unroll
            for (int e = 0; e < 3; ++e) {
                int tz = bz + e - 1;
                if (tz < 0 || tz >= G) continue;
                float w = wxy * wz[e];
                float2* cell = gbase + rowoff + tz;
                atomicAdd(&cell->x, w);
                atomicAdd(&cell->y, w * p);
            }
        }
    }
}

__global__ void finalize_interleaved(const float2* __restrict__ grid,
                                     float* __restrict__ out, int n) {
    int i = blockIdx.x * blockDim.x + threadIdx.x;
    if (i >= n) return;
    float2 c = grid[i];
    out[i] = c.y / (c.x + EPS_DIV);
}

} // anonymous namespace

extern "C" void kernel_launch(void* const* d_in, const int* in_sizes, int n_in,
                              void* d_out, int out_size, void* d_ws, size_t ws_size,
                              hipStream_t stream) {
    const float* pos  = (const float*)d_in[0];
    const float* prob = (const float*)d_in[1];
    const int*   bidx = (const int*)d_in[2];
    float* out = (float*)d_out;

    const int L = in_sizes[1];            // prob has L elements
    const int B = out_size / G3;          // out_size == B * G3
    const int nbins = B * BINS_PB;

    const int threads = 256;

    // ws layout: [tiles: nbins*TILE3*8B][slots: nbins*CAP*16B][cnt: nbins*4B]
    const size_t tiles_bytes = (size_t)nbins * TILE3 * sizeof(float2);
    const size_t slots_bytes = (size_t)nbins * CAP * sizeof(float4);
    const size_t cnt_bytes   = (size_t)nbins * sizeof(int);
    const size_t need        = tiles_bytes + slots_bytes + cnt_bytes;

    if (ws_size >= need) {
        float2* tiles = (float2*)d_ws;
        float4* slots = (float4*)((char*)d_ws + tiles_bytes);
        int*    cnt   = (int*)((char*)d_ws + tiles_bytes + slots_bytes);

        hipMemsetAsync(cnt, 0, cnt_bytes, stream);
        bin_particles_xcd<<<B * STRIPES, threads, 0, stream>>>(pos, prob, bidx,
                                                               cnt, slots, L, B);
        accumulate_bins<<<B * BINS_PB, threads, 0, stream>>>(slots, cnt, tiles, B);
        finalize_tiles<<<B * (G3 / threads), threads, 0, stream>>>(tiles, out, B);
    } else if (ws_size >= (size_t)out_size * 2 * sizeof(float)) {
        // v1 fallback: interleaved global-atomic scatter
        const int pblocks = (L + threads - 1) / threads;
        const int fblocks = (out_size + threads - 1) / threads;
        float2* grid = (float2*)d_ws;
        hipMemsetAsync(d_ws, 0, (size_t)out_size * 2 * sizeof(float), stream);
        scatter_interleaved<<<pblocks, threads, 0, stream>>>(pos, prob, bidx, grid, L);
        finalize_interleaved<<<fblocks, threads, 0, stream>>>(grid, out, out_size);
    }
}

// Round 8
// 181.744 us; speedup vs baseline: 1.3454x; 1.3454x over previous
//
#include <hip/hip_runtime.h>

// P2G quadratic B-spline scatter, MI355X — v7: v5 revert + micro-opts.
//
// v6 post-mortem: XCD-batch partitioning REGRESSED (76 -> 135 us): the
// bidx==k filter made pos reads 1M sparse scattered loads + 8x bidx re-read
// (FETCH 10 -> 68 MB), while WRITE only dropped 59 -> 45 MB. Lesson:
// scatter is conserved across the pipeline (v2 gather-side == v3
// scatter-side == v6 read-side). v5's decomposition is scatter-minimal:
// 1M counter atomics + 1M payload stores at the measured ~26 G-op/s
// scattered-transaction wall -> K1 ~= 76 us structural floor.
//   K1: bin particles; slot = atomicAdd(cnt[bin]); slots[bin*CAP+slot] =
//       {clipped px,py,pz, prob}  (clip hoisted here, K2 reuses)
//   K2: one workgroup per bin; coalesced slot reads; 27 taps x 2 native
//       ds_add_u64 (2^42 fixed point) into 10^3 LDS tile; float2 store.
//   K3: per cell, fp32-sum the 1..8 covering tiles, out = wp/(w+1e-7).
// Fallback (ws too small): v1 interleaved global-atomic path.

namespace {

constexpr int   G        = 64;
constexpr int   G3       = G * G * G;            // 262144
constexpr int   BIN      = 8;                    // cells per bin per axis
constexpr int   NBX      = G / BIN;              // 8 bins per axis
constexpr int   BINS_PB  = NBX * NBX * NBX;      // 512 bins per batch
constexpr int   TILE     = BIN + 2;              // 10 (halo -1..8)
constexpr int   TILE3    = TILE * TILE * TILE;   // 1000
constexpr int   CAP      = 512;                  // slots per bin (avg ~244)
constexpr float EPS_CLIP = 1e-5f;
constexpr float EPS_DIV  = 1e-7f;
constexpr float INV_DX   = 64.0f;                // 1/DX (exact pow2)
constexpr float FXS      = 4398046511104.0f;     // 2^42 fixed-point scale
constexpr float INV_FXS  = 1.0f / FXS;           // 2^-42

__device__ __forceinline__ float clip01(float v) {
    return fminf(fmaxf(v, EPS_CLIP), 1.0f - EPS_CLIP);
}

__device__ __forceinline__ void bspline_w(float f, float* w) {
    w[0] = 0.5f * (1.0f - f) * (1.0f - f);
    w[1] = 0.75f - (f - 0.5f) * (f - 0.5f);
    w[2] = 0.5f * f * f;
}

// ---------------- K1: bin particles, materialize clipped payload ----------

__global__ void bin_particles_mat(const float* __restrict__ pos,
                                  const float* __restrict__ prob,
                                  const int*   __restrict__ bidx,
                                  int*         __restrict__ cnt,    // nbins
                                  float4*      __restrict__ slots,  // nbins*CAP
                                  int L) {
    int i = blockIdx.x * blockDim.x + threadIdx.x;
    if (i >= L) return;
    float px = clip01(pos[3 * i + 0]);
    float py = clip01(pos[3 * i + 1]);
    float pz = clip01(pos[3 * i + 2]);
    int bx = (int)(px * INV_DX);
    int by = (int)(py * INV_DX);
    int bz = (int)(pz * INV_DX);
    int bin = ((bidx[i] * NBX + (bx >> 3)) * NBX + (by >> 3)) * NBX + (bz >> 3);
    int slot = atomicAdd(&cnt[bin], 1);
    if (slot < CAP) slots[(size_t)bin * CAP + slot] = make_float4(px, py, pz, prob[i]);
}

// ---------------- K2: per-bin LDS tile accumulation (2x ds_add_u64) -------

__global__ void __launch_bounds__(256)
accumulate_bins(const float4* __restrict__ slots,
                const int*    __restrict__ cnt,
                float2*       __restrict__ tiles) {   // nbins*TILE3
    __shared__ unsigned long long t_w[TILE3];
    __shared__ unsigned long long t_wp[TILE3];
    const int bin = blockIdx.x;
    const int tid = threadIdx.x;

    for (int j = tid; j < TILE3; j += 256) { t_w[j] = 0ull; t_wp[j] = 0ull; }
    __syncthreads();

    const int n = min(cnt[bin], CAP);
    // bin origin in cells (bin = ((b*8+bbx)*8+bby)*8+bbz)
    const int bx0 = ((bin >> 6) & 7) * BIN;
    const int by0 = ((bin >> 3) & 7) * BIN;
    const int bz0 = (bin & 7) * BIN;
    const float4* sbase = slots + (size_t)bin * CAP;

    for (int s = tid; s < n; s += 256) {
        float4 r = sbase[s];                         // coalesced 16B load
        float xp = r.x * INV_DX;                     // pos pre-clipped in K1
        float yp = r.y * INV_DX;
        float zp = r.z * INV_DX;
        int bx = (int)xp, by = (int)yp, bz = (int)zp;
        float wx[3], wy[3], wz[3];
        bspline_w(xp - (float)bx, wx);
        bspline_w(yp - (float)by, wy);
        bspline_w(zp - (float)bz, wz);
        float p = r.w;
        // local base, pre-offset so tap index = l0 + a directly in [0, 9]
        int l0x = bx - bx0, l0y = by - by0, l0z = bz - bz0;
#pragma unroll
        for (int a = 0; a < 3; ++a) {
            int ix = (l0x + a) * TILE;
#pragma unroll
            for (int c = 0; c < 3; ++c) {
                int ixy = (ix + l0y + c) * TILE;
                float wxy = wx[a] * wy[c];
#pragma unroll
                for (int e = 0; e < 3; ++e) {
                    float w  = wxy * wz[e];
                    int   ci = ixy + l0z + e;
                    atomicAdd(&t_w[ci],  (unsigned long long)(w * FXS));
                    atomicAdd(&t_wp[ci], (unsigned long long)(w * p * FXS));
                }
            }
        }
    }
    __syncthreads();

    float2* gt = tiles + (size_t)bin * TILE3;
    for (int j = tid; j < TILE3; j += 256) {
        gt[j] = make_float2((float)t_w[j] * INV_FXS, (float)t_wp[j] * INV_FXS);
    }
}

// ---------------- K3: gather overlapping tiles + divide -------------------

__global__ void finalize_tiles(const float2* __restrict__ tiles,
                               float*        __restrict__ out,
                               int total) {
    int c = blockIdx.x * blockDim.x + threadIdx.x;
    if (c >= total) return;
    int cz = c & 63, cy = (c >> 6) & 63, cx = (c >> 12) & 63, b = c >> 18;
    int bx = cx >> 3, mx = cx & 7;
    int by = cy >> 3, my = cy & 7;
    int bz = cz >> 3, mz = cz & 7;

    // per-axis list of (bin coord, tile-local index) covering this cell
    int xb[2], xl[2], nx = 1; xb[0] = bx; xl[0] = mx + 1;
    if (mx == 0 && bx > 0)       { xb[1] = bx - 1; xl[1] = 9; nx = 2; }
    else if (mx == 7 && bx < 7)  { xb[1] = bx + 1; xl[1] = 0; nx = 2; }
    int yb[2], yl[2], ny = 1; yb[0] = by; yl[0] = my + 1;
    if (my == 0 && by > 0)       { yb[1] = by - 1; yl[1] = 9; ny = 2; }
    else if (my == 7 && by < 7)  { yb[1] = by + 1; yl[1] = 0; ny = 2; }
    int zb[2], zl[2], nz = 1; zb[0] = bz; zl[0] = mz + 1;
    if (mz == 0 && bz > 0)       { zb[1] = bz - 1; zl[1] = 9; nz = 2; }
    else if (mz == 7 && bz < 7)  { zb[1] = bz + 1; zl[1] = 0; nz = 2; }

    float w = 0.f, wp = 0.f;
    for (int i = 0; i < nx; ++i)
        for (int j = 0; j < ny; ++j)
            for (int k = 0; k < nz; ++k) {
                int bin = ((b * NBX + xb[i]) * NBX + yb[j]) * NBX + zb[k];
                float2 v = tiles[(size_t)bin * TILE3
                                 + (xl[i] * TILE + yl[j]) * TILE + zl[k]];
                w += v.x; wp += v.y;
            }
    out[c] = wp / (w + EPS_DIV);
}

// ---------------- fallback kernels (v1) -----------------------------------

__global__ void scatter_interleaved(const float* __restrict__ pos,
                                    const float* __restrict__ prob,
                                    const int*   __restrict__ bidx,
                                    float2*      __restrict__ grid,
                                    int L) {
    int i = blockIdx.x * blockDim.x + threadIdx.x;
    if (i >= L) return;
    float xp = clip01(pos[3 * i + 0]) * INV_DX;
    float yp = clip01(pos[3 * i + 1]) * INV_DX;
    float zp = clip01(pos[3 * i + 2]) * INV_DX;
    int bx = (int)xp, by = (int)yp, bz = (int)zp;
    float wx[3], wy[3], wz[3];
    bspline_w(xp - (float)bx, wx);
    bspline_w(yp - (float)by, wy);
    bspline_w(zp - (float)bz, wz);
    float p = prob[i];
    float2* gbase = grid + (size_t)bidx[i] * G3;
#pragma unroll
    for (int a = 0; a < 3; ++a) {
        int tx = bx + a - 1;
        if (tx < 0 || tx >= G) continue;
#pragma unroll
        for (int c = 0; c < 3; ++c) {
            int ty = by + c - 1;
            if (ty < 0 || ty >= G) continue;
            float wxy = wx[a] * wy[c];
            int rowoff = (tx * G + ty) * G;
#pragma unroll
            for (int e = 0; e < 3; ++e) {
                int tz = bz + e - 1;
                if (tz < 0 || tz >= G) continue;
                float w = wxy * wz[e];
                float2* cell = gbase + rowoff + tz;
                atomicAdd(&cell->x, w);
                atomicAdd(&cell->y, w * p);
            }
        }
    }
}

__global__ void finalize_interleaved(const float2* __restrict__ grid,
                                     float* __restrict__ out, int n) {
    int i = blockIdx.x * blockDim.x + threadIdx.x;
    if (i >= n) return;
    float2 c = grid[i];
    out[i] = c.y / (c.x + EPS_DIV);
}

} // anonymous namespace

extern "C" void kernel_launch(void* const* d_in, const int* in_sizes, int n_in,
                              void* d_out, int out_size, void* d_ws, size_t ws_size,
                              hipStream_t stream) {
    const float* pos  = (const float*)d_in[0];
    const float* prob = (const float*)d_in[1];
    const int*   bidx = (const int*)d_in[2];
    float* out = (float*)d_out;

    const int L = in_sizes[1];            // prob has L elements
    const int B = out_size / G3;          // out_size == B * G3
    const int nbins = B * BINS_PB;

    const int threads = 256;
    const int pblocks = (L + threads - 1) / threads;
    const int fblocks = (out_size + threads - 1) / threads;

    // ws layout: [tiles: nbins*TILE3*8B][slots: nbins*CAP*16B][cnt: nbins*4B]
    const size_t tiles_bytes = (size_t)nbins * TILE3 * sizeof(float2);
    const size_t slots_bytes = (size_t)nbins * CAP * sizeof(float4);
    const size_t cnt_bytes   = (size_t)nbins * sizeof(int);
    const size_t need        = tiles_bytes + slots_bytes + cnt_bytes;

    if (ws_size >= need) {
        float2* tiles = (float2*)d_ws;
        float4* slots = (float4*)((char*)d_ws + tiles_bytes);
        int*    cnt   = (int*)((char*)d_ws + tiles_bytes + slots_bytes);

        hipMemsetAsync(cnt, 0, cnt_bytes, stream);
        bin_particles_mat<<<pblocks, threads, 0, stream>>>(pos, prob, bidx,
                                                           cnt, slots, L);
        accumulate_bins<<<nbins, threads, 0, stream>>>(slots, cnt, tiles);
        finalize_tiles<<<fblocks, threads, 0, stream>>>(tiles, out, out_size);
    } else if (ws_size >= (size_t)out_size * 2 * sizeof(float)) {
        // v1 fallback: interleaved global-atomic scatter
        float2* grid = (float2*)d_ws;
        hipMemsetAsync(d_ws, 0, (size_t)out_size * 2 * sizeof(float), stream);
        scatter_interleaved<<<pblocks, threads, 0, stream>>>(pos, prob, bidx, grid, L);
        finalize_interleaved<<<fblocks, threads, 0, stream>>>(grid, out, out_size);
    }
}